// Round 1
// baseline (619.031 us; speedup 1.0000x reference)
//
#include <hip/hip_runtime.h>

// DTCWT 1D forward, 3 levels, fused single kernel.
// x: [64, 1, 2^20] fp32. Outputs concatenated flat:
//   lo3 [64,1,131072] | yh0 [64,1,1,524288] | yh1 [64,2,1,262144] | yh2 [64,2,1,131072]

#define BS   256
#define T3   512          // level-3 outputs per block
#define T2   (2*T3)
#define T1   (4*T3)
#define XOFF 40
#define XCNT (8*T3 + 80)  // x tile incl. halo
#define L1CNT (T1 + 36)   // lo1 tile incl. +/-18 halo
#define L2CNT (T2 + 12)   // lo2 tile incl. +/-6 halo

__global__ __launch_bounds__(BS) void dtcwt3_kernel(
    const float* __restrict__ x,
    const float* __restrict__ h0o, const float* __restrict__ h1o,
    const float* __restrict__ h0a, const float* __restrict__ h1a,
    const float* __restrict__ h1b,
    float* __restrict__ lo3, float* __restrict__ yh0,
    float* __restrict__ yh1, float* __restrict__ yh2)
{
    const int L  = 1 << 20;
    const int N1 = L >> 1, N2 = L >> 2, N3 = L >> 3;
    const int tilesPerRow = N3 / T3;      // 256
    const int b  = blockIdx.x / tilesPerRow;
    const int tl = blockIdx.x % tilesPerRow;
    const int M3 = tl * T3;
    const int M2 = 2 * M3, M1 = 4 * M3, MX = 8 * M3;
    const int tid = threadIdx.x;

    __shared__ float xs[XCNT];
    __shared__ float l1[L1CNT];
    __shared__ float l2[L2CNT];

    // Filters into registers (uniform across threads).
    float f0o[5], f1o[7], f0a[14], f1a[14], f1b[14];
#pragma unroll
    for (int i = 0; i < 5;  ++i) f0o[i] = h0o[i];
#pragma unroll
    for (int i = 0; i < 7;  ++i) f1o[i] = h1o[i];
#pragma unroll
    for (int i = 0; i < 14; ++i) f0a[i] = h0a[i];
#pragma unroll
    for (int i = 0; i < 14; ++i) f1a[i] = h1a[i];
#pragma unroll
    for (int i = 0; i < 14; ++i) f1b[i] = h1b[i];

    // ---- Phase A: stage x tile (zero-padded) into LDS ----
    const float* xrow = x + (size_t)b * L;
    for (int i = tid; i < XCNT; i += BS) {
        int gx = MX - XOFF + i;
        xs[i] = (gx >= 0 && gx < L) ? xrow[gx] : 0.0f;
    }
    __syncthreads();

    // ---- Phase B: level 1 ----
    // lo1 halo entries (18 each side); zero outside [0,N1)
    for (int i = tid; i < 36; i += BS) {
        int slot = (i < 18) ? i : (T1 + i);          // 0..17 | T1+18..T1+35
        int q = M1 - 18 + slot;
        float v = 0.0f;
        if (q >= 0 && q < N1) {
            int xb = 2 * q - 2 - (MX - XOFF);
            v = xs[xb]   * f0o[0] + xs[xb+1] * f0o[1] + xs[xb+2] * f0o[2]
              + xs[xb+3] * f0o[3] + xs[xb+4] * f0o[4];
        }
        l1[slot] = v;
    }
    // core: lo1 + hi1 share the 7-wide window
    for (int i = tid; i < T1; i += BS) {
        int q  = M1 + i;                   // in [0,N1) always
        int xb = 2 * q - 3 - (MX - XOFF);
        float w0 = xs[xb+0], w1 = xs[xb+1], w2 = xs[xb+2], w3 = xs[xb+3],
              w4 = xs[xb+4], w5 = xs[xb+5], w6 = xs[xb+6];
        float hi = w0*f1o[0] + w1*f1o[1] + w2*f1o[2] + w3*f1o[3]
                 + w4*f1o[4] + w5*f1o[5] + w6*f1o[6];
        float lo = w1*f0o[0] + w2*f0o[1] + w3*f0o[2] + w4*f0o[3] + w5*f0o[4];
        l1[18 + i] = lo;
        yh0[(size_t)b * N1 + q] = hi;
    }
    __syncthreads();

    // ---- Phase C: level 2 ----
    // lo2 halo entries (6 each side)
    for (int i = tid; i < 12; i += BS) {
        int slot = (i < 6) ? i : (T2 + i);           // 0..5 | T2+6..T2+11
        int p = M2 - 6 + slot;
        float v = 0.0f;
        if (p >= 0 && p < N2) {
            int lb = 2 * p - 6 - (M1 - 18);
#pragma unroll
            for (int t = 0; t < 14; ++t) v += l1[lb + t] * f0a[t];
        }
        l2[slot] = v;
    }
    // core: lo2 + hia + hib share the 14-wide window
    for (int i = tid; i < T2; i += BS) {
        int p  = M2 + i;                   // in [0,N2)
        int lb = 12 + 2 * i;               // = 2p-6-(M1-18)
        float w[14];
#pragma unroll
        for (int t = 0; t < 14; ++t) w[t] = l1[lb + t];
        float lo = 0.f, va = 0.f, vb = 0.f;
#pragma unroll
        for (int t = 0; t < 14; ++t) {
            lo += w[t] * f0a[t];
            va += w[t] * f1a[t];
            vb += w[t] * f1b[t];
        }
        l2[6 + i] = lo;
        size_t base = (size_t)b * 2 * N2;
        yh1[base + p]      = va;
        yh1[base + N2 + p] = vb;
    }
    __syncthreads();

    // ---- Phase D: level 3 ----
    for (int i = tid; i < T3; i += BS) {
        int m  = M3 + i;
        int lb = 2 * i;                    // = 2m-6-(M2-6)
        float w[14];
#pragma unroll
        for (int t = 0; t < 14; ++t) w[t] = l2[lb + t];
        float lo = 0.f, va = 0.f, vb = 0.f;
#pragma unroll
        for (int t = 0; t < 14; ++t) {
            lo += w[t] * f0a[t];
            va += w[t] * f1a[t];
            vb += w[t] * f1b[t];
        }
        lo3[(size_t)b * N3 + m] = lo;
        size_t base = (size_t)b * 2 * N3;
        yh2[base + m]      = va;
        yh2[base + N3 + m] = vb;
    }
}

extern "C" void kernel_launch(void* const* d_in, const int* in_sizes, int n_in,
                              void* d_out, int out_size, void* d_ws, size_t ws_size,
                              hipStream_t stream) {
    const float* x   = (const float*)d_in[0];
    const float* h0o = (const float*)d_in[1];
    const float* h1o = (const float*)d_in[2];
    const float* h0a = (const float*)d_in[3];
    const float* h1a = (const float*)d_in[4];
    // d_in[5] = h0b: unused by the reference computation
    const float* h1b = (const float*)d_in[6];

    float* out = (float*)d_out;
    // B=64, N1=524288, N2=262144, N3=131072
    float* lo3 = out;                        // 64*131072      = 8388608
    float* yh0 = out + 8388608;              // 64*524288      = 33554432
    float* yh1 = out + 41943040;             // 64*2*262144    = 33554432
    float* yh2 = out + 75497472;             // 64*2*131072    = 16777216

    const int tilesPerRow = 131072 / T3;     // 256
    dim3 grid(64 * tilesPerRow);             // 16384 blocks
    dtcwt3_kernel<<<grid, BS, 0, stream>>>(x, h0o, h1o, h0a, h1a, h1b,
                                           lo3, yh0, yh1, yh2);
}

// Round 2
// 547.837 us; speedup vs baseline: 1.1300x; 1.1300x over previous
//
#include <hip/hip_runtime.h>

// DTCWT 1D forward, 3 levels, fused single kernel — vectorized LDS/global I/O.
// x: [64, 1, 2^20] fp32. Outputs concatenated flat:
//   lo3 [64,1,131072] | yh0 [64,1,1,524288] | yh1 [64,2,1,262144] | yh2 [64,2,1,131072]

#define BS    256
#define T3    512
#define T2    1024
#define T1    2048
#define XCNT  4176   // 8*T3 + 80, covers x [MX-40, MX+8*T3+40)
#define L1CNT 2084   // T1 + 36   (halo 18 each side)
#define L2CNT 1036   // T2 + 12   (halo 6 each side)

typedef float f4 __attribute__((ext_vector_type(4)));
typedef float f2 __attribute__((ext_vector_type(2)));

__global__ __launch_bounds__(BS, 5) void dtcwt3_kernel(
    const float* __restrict__ x,
    const float* __restrict__ h0o, const float* __restrict__ h1o,
    const float* __restrict__ h0a, const float* __restrict__ h1a,
    const float* __restrict__ h1b,
    float* __restrict__ lo3, float* __restrict__ yh0,
    float* __restrict__ yh1, float* __restrict__ yh2)
{
    const int L  = 1 << 20;
    const int N1 = L >> 1, N2 = L >> 2, N3 = L >> 3;
    const int tilesPerRow = N3 / T3;      // 256
    const int b  = blockIdx.x / tilesPerRow;
    const int tl = blockIdx.x % tilesPerRow;
    const int M3 = tl * T3;
    const int M2 = 2 * M3, M1 = 4 * M3, MX = 8 * M3;
    const int tid = threadIdx.x;

    __shared__ __align__(16) float xs[XCNT];
    __shared__ __align__(16) float l1[L1CNT];
    __shared__ __align__(16) float l2[L2CNT];

    float f0o[5], f1o[7], f0a[14], f1a[14], f1b[14];
#pragma unroll
    for (int i = 0; i < 5;  ++i) f0o[i] = h0o[i];
#pragma unroll
    for (int i = 0; i < 7;  ++i) f1o[i] = h1o[i];
#pragma unroll
    for (int i = 0; i < 14; ++i) f0a[i] = h0a[i];
#pragma unroll
    for (int i = 0; i < 14; ++i) f1a[i] = h1a[i];
#pragma unroll
    for (int i = 0; i < 14; ++i) f1b[i] = h1b[i];

    // ---- Phase A: stage x tile into LDS (float4 path for interior tiles) ----
    const float* xrow = x + (size_t)b * L;
    const int xbase = MX - 40;            // multiple of 4 (MX mult of 4096)
    if (tl > 0 && tl < tilesPerRow - 1) {
        for (int k = tid; k < XCNT / 4; k += BS) {     // 1044 float4s
            *(f4*)(xs + 4 * k) = *(const f4*)(xrow + xbase + 4 * k);
        }
    } else {
        for (int i = tid; i < XCNT; i += BS) {
            int gx = xbase + i;
            xs[i] = (gx >= 0 && gx < L) ? xrow[gx] : 0.0f;
        }
    }
    __syncthreads();

    // ---- Phase B: level 1 ----
    // lo1 halo (18 each side); zero outside [0,N1)
    if (tid < 36) {
        int slot = (tid < 18) ? tid : (T1 + tid);      // 0..17 | 2066..2083
        int q = M1 - 18 + slot;
        float v = 0.0f;
        if (q >= 0 && q < N1) {
            int xb = 2 * q - 2 - xbase;
            v = xs[xb]   * f0o[0] + xs[xb+1] * f0o[1] + xs[xb+2] * f0o[2]
              + xs[xb+3] * f0o[3] + xs[xb+4] * f0o[4];
        }
        l1[slot] = v;
    }
    // core: 8 outputs/thread, window x[2q0-4 .. 2q0+19] via 6x b128
    {
        const int q0 = M1 + 8 * tid;
        const int sb = 16 * tid + 36;                  // 16B-aligned slot
        float w[24];
#pragma unroll
        for (int k = 0; k < 6; ++k) {
            f4 v = *(const f4*)(xs + sb + 4 * k);
            w[4*k] = v.x; w[4*k+1] = v.y; w[4*k+2] = v.z; w[4*k+3] = v.w;
        }
        float hi[8], lo[8];
#pragma unroll
        for (int j = 0; j < 8; ++j) {
            float h = 0.f;
#pragma unroll
            for (int t = 0; t < 7; ++t) h += w[2*j + 1 + t] * f1o[t];
            float l = 0.f;
#pragma unroll
            for (int t = 0; t < 5; ++t) l += w[2*j + 2 + t] * f0o[t];
            hi[j] = h; lo[j] = l;
        }
#pragma unroll
        for (int k = 0; k < 4; ++k) {
            f2 v = { lo[2*k], lo[2*k+1] };
            *(f2*)(l1 + 18 + 8 * tid + 2 * k) = v;     // even slot -> b64
        }
        float* yrow = yh0 + (size_t)b * N1 + q0;
        f4 h0v = { hi[0], hi[1], hi[2], hi[3] };
        f4 h1v = { hi[4], hi[5], hi[6], hi[7] };
        *(f4*)(yrow)     = h0v;
        *(f4*)(yrow + 4) = h1v;
    }
    __syncthreads();

    // ---- Phase C: level 2 ----
    // lo2 halo (6 each side); zero outside [0,N2)
    if (tid < 12) {
        int slot = (tid < 6) ? tid : (T2 + tid);       // 0..5 | 1030..1035
        int p = M2 - 6 + slot;
        float v = 0.0f;
        if (p >= 0 && p < N2) {
            int lb = 2 * p - 6 - (M1 - 18);
#pragma unroll
            for (int t = 0; t < 14; ++t) v += l1[lb + t] * f0a[t];
        }
        l2[slot] = v;
    }
    // core: 4 outputs/thread, window l1 slots [8t+12 .. 8t+31] via 5x b128
    {
        const int p0 = M2 + 4 * tid;
        const int sb = 8 * tid + 12;                   // 16B-aligned slot
        float w[20];
#pragma unroll
        for (int k = 0; k < 5; ++k) {
            f4 v = *(const f4*)(l1 + sb + 4 * k);
            w[4*k] = v.x; w[4*k+1] = v.y; w[4*k+2] = v.z; w[4*k+3] = v.w;
        }
        float lo[4], va[4], vb[4];
#pragma unroll
        for (int j = 0; j < 4; ++j) {
            float a = 0.f, c = 0.f, d = 0.f;
#pragma unroll
            for (int t = 0; t < 14; ++t) {
                float ww = w[2*j + t];
                a += ww * f0a[t]; c += ww * f1a[t]; d += ww * f1b[t];
            }
            lo[j] = a; va[j] = c; vb[j] = d;
        }
        f2 l01 = { lo[0], lo[1] }, l23 = { lo[2], lo[3] };
        *(f2*)(l2 + 6 + 4 * tid)     = l01;            // even slot -> b64
        *(f2*)(l2 + 6 + 4 * tid + 2) = l23;
        size_t base = (size_t)b * 2 * N2;
        f4 av = { va[0], va[1], va[2], va[3] };
        f4 bv = { vb[0], vb[1], vb[2], vb[3] };
        *(f4*)(yh1 + base + p0)      = av;
        *(f4*)(yh1 + base + N2 + p0) = bv;
    }
    __syncthreads();

    // ---- Phase D: level 3 ----
    // 2 outputs/thread, window l2 slots [4t .. 4t+15] via 4x b128
    {
        const int m0 = M3 + 2 * tid;
        const int sb = 4 * tid;                        // 16B-aligned slot
        float w[16];
#pragma unroll
        for (int k = 0; k < 4; ++k) {
            f4 v = *(const f4*)(l2 + sb + 4 * k);
            w[4*k] = v.x; w[4*k+1] = v.y; w[4*k+2] = v.z; w[4*k+3] = v.w;
        }
        float lo[2], va[2], vb[2];
#pragma unroll
        for (int j = 0; j < 2; ++j) {
            float a = 0.f, c = 0.f, d = 0.f;
#pragma unroll
            for (int t = 0; t < 14; ++t) {
                float ww = w[2*j + t];
                a += ww * f0a[t]; c += ww * f1a[t]; d += ww * f1b[t];
            }
            lo[j] = a; va[j] = c; vb[j] = d;
        }
        f2 lv = { lo[0], lo[1] };
        f2 av = { va[0], va[1] };
        f2 bv = { vb[0], vb[1] };
        *(f2*)(lo3 + (size_t)b * N3 + m0) = lv;
        size_t base = (size_t)b * 2 * N3;
        *(f2*)(yh2 + base + m0)      = av;
        *(f2*)(yh2 + base + N3 + m0) = bv;
    }
}

extern "C" void kernel_launch(void* const* d_in, const int* in_sizes, int n_in,
                              void* d_out, int out_size, void* d_ws, size_t ws_size,
                              hipStream_t stream) {
    const float* x   = (const float*)d_in[0];
    const float* h0o = (const float*)d_in[1];
    const float* h1o = (const float*)d_in[2];
    const float* h0a = (const float*)d_in[3];
    const float* h1a = (const float*)d_in[4];
    // d_in[5] = h0b: unused by the reference computation
    const float* h1b = (const float*)d_in[6];

    float* out = (float*)d_out;
    float* lo3 = out;                        // 64*131072
    float* yh0 = out + 8388608;              // 64*524288
    float* yh1 = out + 41943040;             // 64*2*262144
    float* yh2 = out + 75497472;             // 64*2*131072

    const int tilesPerRow = 131072 / T3;     // 256
    dim3 grid(64 * tilesPerRow);             // 16384 blocks
    dtcwt3_kernel<<<grid, BS, 0, stream>>>(x, h0o, h1o, h0a, h1a, h1b,
                                           lo3, yh0, yh1, yh2);
}